// Round 7
// baseline (340.612 us; speedup 1.0000x reference)
//
#include <hip/hip_runtime.h>
#include <hip/hip_cooperative_groups.h>
#include <hip/hip_bf16.h>
#include <math.h>

namespace cg = cooperative_groups;

#define TT   1024
#define HH   1024
#define II   512
#define EE   32
#define NE   40
#define TOPK 4
#define CAP  1024

#define GM  128   // m-tile (slots)
#define GNP 32    // gate/up pairs per block
#define GK  32    // k-slab per MFMA step
#define DN  64    // down n-tile

typedef __attribute__((ext_vector_type(4))) short short4v;
typedef __attribute__((ext_vector_type(8))) short short8v;
typedef __attribute__((ext_vector_type(4))) float floatx4;

static __device__ __forceinline__ short f2bf(float f) {
    unsigned u = __float_as_uint(f);
    unsigned r = (u + 0x7fffu + ((u >> 16) & 1u)) >> 16;
    return (short)(r & 0xffffu);
}
static __device__ __forceinline__ float bf2f(short s) {
    return __uint_as_float(((unsigned)(unsigned short)s) << 16);
}
#if defined(__has_builtin)
#if __has_builtin(__builtin_amdgcn_cvt_pk_bf16_f32)
#define HAVE_PK_BF16 1
#endif
#endif
static __device__ __forceinline__ unsigned pk2(float a, float b) {
#ifdef HAVE_PK_BF16
    typedef __attribute__((ext_vector_type(2))) __bf16 bf2t;
    union { bf2t v; unsigned u; } cv;
    cv.v = __builtin_amdgcn_cvt_pk_bf16_f32(a, b);
    return cv.u;
#else
    return (unsigned)(unsigned short)f2bf(a) | ((unsigned)(unsigned short)f2bf(b) << 16);
#endif
}
static __device__ __forceinline__ short4v cvt4(float4 v) {
    union { unsigned u[2]; short4v s; } cv;
    cv.u[0] = pk2(v.x, v.y); cv.u[1] = pk2(v.z, v.w);
    return cv.s;
}
// 8 fp32 (two float4, consecutive k) -> 8 bf16 frag
static __device__ __forceinline__ short8v pack8(float4 a, float4 b) {
    union { unsigned u[4]; short8v s; } cv;
    cv.u[0] = pk2(a.x, a.y); cv.u[1] = pk2(a.z, a.w);
    cv.u[2] = pk2(b.x, b.y); cv.u[3] = pk2(b.z, b.w);
    return cv.s;
}

// tiny shared block: slot list + weights only (no GEMM staging!)
struct SMem {
    int   sl[GM];
    float wvs[GM];
};

// ---------------- workspace layout (bytes) ----------------
// counts @0, topk_w @1024, zero_w @17408, kexp @21504, slots @40960,
// xb @262144 (2MB), hmid @2359296 (4MB), ydown @6553600 (8MB)

// ================= Phase A: router (waves 0,1) + xconv (waves 2,3) ============
static __device__ __forceinline__ void phaseA(
    const int bx, const int tid,
    const float* __restrict__ x, const float* __restrict__ rw,
    const float* __restrict__ bias,
    float* __restrict__ topk_w, float* __restrict__ zero_w,
    int* __restrict__ kexp, int* __restrict__ counts,
    int* __restrict__ slots, short* __restrict__ xb)
{
    const int lane = tid & 63;
    const int w    = tid >> 6;

    if (w < 2) {
        const int t = bx * 2 + w;
        float xv[16];
        #pragma unroll
        for (int i = 0; i < 16; ++i) xv[i] = x[(size_t)t * HH + 64 * i + lane];

        float mylogit = -INFINITY;
        for (int e0 = 0; e0 < NE; e0 += 4) {
            const float* r0 = rw + (size_t)e0 * HH;
            float p[4] = { 0.f, 0.f, 0.f, 0.f };
            #pragma unroll
            for (int i = 0; i < 16; ++i) {
                int h = 64 * i + lane;
                #pragma unroll
                for (int j = 0; j < 4; ++j) p[j] += xv[i] * r0[(size_t)j * HH + h];
            }
            #pragma unroll
            for (int j = 0; j < 4; ++j) {
                #pragma unroll
                for (int off = 32; off > 0; off >>= 1) p[j] += __shfl_xor(p[j], off);
                if (lane == e0 + j) mylogit = p[j];
            }
        }

        float m = mylogit;
        #pragma unroll
        for (int off = 32; off > 0; off >>= 1) m = fmaxf(m, __shfl_xor(m, off));
        float pexp = (lane < NE) ? expf(mylogit - m) : 0.f;
        float s = pexp;
        #pragma unroll
        for (int off = 32; off > 0; off >>= 1) s += __shfl_xor(s, off);
        const float score = pexp / s;

        float val = (lane < NE) ? score + bias[lane] : -INFINITY;
        int   kidx[TOPK];
        float kw[TOPK];
        #pragma unroll
        for (int k = 0; k < TOPK; ++k) {
            float v = val; int idx = lane;
            #pragma unroll
            for (int off = 32; off > 0; off >>= 1) {
                float ov = __shfl_xor(v, off);
                int   oi = __shfl_xor(idx, off);
                if (ov > v || (ov == v && oi < idx)) { v = ov; idx = oi; }
            }
            kidx[k] = idx;
            kw[k]   = __shfl(score, idx);
            if (lane == idx) val = -INFINITY;
        }

        if (lane == 0) {
            float zw = 0.f;
            #pragma unroll
            for (int k = 0; k < TOPK; ++k) {
                int slot = t * TOPK + k;
                topk_w[slot] = kw[k];
                kexp[slot]   = kidx[k];
                if (kidx[k] < EE) {
                    int pos = atomicAdd(&counts[kidx[k]], 1);
                    slots[kidx[k] * CAP + pos] = slot;
                } else {
                    zw += kw[k];
                }
            }
            zero_w[t] = zw;
        }
    } else {
        const int t = bx * 2 + (w - 2);
        const float4* xr = (const float4*)(x + (size_t)t * HH);
        short4v* xbr = (short4v*)(xb + (size_t)t * HH);
        #pragma unroll
        for (int i = 0; i < 4; ++i) xbr[lane + 64 * i] = cvt4(xr[lane + 64 * i]);
    }
}

// ================= Phase B: gate_up — LDS-free direct-fragment MFMA ===========
static __device__ __forceinline__ void phaseB(
    const int bx, const int tid, SMem* sm,
    const short* __restrict__ xb, const float* __restrict__ wgu,
    const int* __restrict__ counts, const int* __restrict__ slots,
    const float* __restrict__ topk_w, short* __restrict__ hmid)
{
    const int e      = bx >> 4;
    const int c_base = (bx & 15) * GNP;
    const int cnt    = counts[e];
    const float* wb  = wgu + (size_t)e * (2 * II) * HH;

    const int lane = tid & 63;
    const int w    = tid >> 6;
    const int wy   = w & 1;     // m-half (64 rows)
    const int wx   = w >> 1;    // n-half (16 pairs)
    const int quad = lane >> 4;
    const int mcol = lane & 15;

    // per-lane B row pointers (read once from HBM, full 128B lines per quad-set)
    const float* pg = wb + (size_t)(c_base + wx * 16 + mcol) * HH + quad * 8;
    const float* pu = pg + (size_t)II * HH;

    for (int m_base = 0; m_base < cnt; m_base += GM) {
        if (tid < GM) {
            int m = m_base + tid;
            int s = (m < cnt) ? slots[e * CAP + m] : -1;
            sm->sl[tid]  = s;
            sm->wvs[tid] = (s >= 0) ? topk_w[s] : 0.f;
        }
        __syncthreads();

        // per-lane A row pointers (gathered token rows, bf16, L2-served)
        const short* pa[4];
        #pragma unroll
        for (int i = 0; i < 4; ++i) {
            int s = sm->sl[wy * 64 + i * 16 + mcol];
            pa[i] = xb + (size_t)(s >= 0 ? (s >> 2) : 0) * HH + quad * 8;
        }

        floatx4 accg[4] = {};
        floatx4 accu[4] = {};

        #pragma unroll 2
        for (int k0 = 0; k0 < HH; k0 += GK) {
            short8v a[4];
            #pragma unroll
            for (int i = 0; i < 4; ++i) a[i] = *(const short8v*)(pa[i] + k0);
            float4 g0 = *(const float4*)(pg + k0);
            float4 g1 = *(const float4*)(pg + k0 + 4);
            float4 u0 = *(const float4*)(pu + k0);
            float4 u1 = *(const float4*)(pu + k0 + 4);
            short8v bg = pack8(g0, g1);
            short8v bu = pack8(u0, u1);
            #pragma unroll
            for (int i = 0; i < 4; ++i) {
                accg[i] = __builtin_amdgcn_mfma_f32_16x16x32_bf16(a[i], bg, accg[i], 0, 0, 0);
                accu[i] = __builtin_amdgcn_mfma_f32_16x16x32_bf16(a[i], bu, accu[i], 0, 0, 0);
            }
        }

        // epilogue: hmid[slot][c] = w * silu(gate) * up
        #pragma unroll
        for (int i = 0; i < 4; ++i) {
            #pragma unroll
            for (int r = 0; r < 4; ++r) {
                int m = wy * 64 + i * 16 + quad * 4 + r;
                int s = sm->sl[m];
                if (s < 0) continue;
                float g = accg[i][r], u = accu[i][r];
                float valf = sm->wvs[m] * g * u / (1.f + __expf(-g));
                hmid[(size_t)s * II + c_base + wx * 16 + mcol] = f2bf(valf);
            }
        }
        __syncthreads();   // protect sl/wvs before next m-tile
    }
}

// ================= Phase C: down — LDS-free direct-fragment MFMA ==============
static __device__ __forceinline__ void phaseC(
    const int bx, const int tid, SMem* sm,
    const short* __restrict__ hmid, const float* __restrict__ wd,
    const int* __restrict__ counts, const int* __restrict__ slots,
    short* __restrict__ ydown)
{
    const int e      = bx >> 4;
    const int n_base = (bx & 15) * DN;
    const int cnt    = counts[e];
    const float* wb  = wd + (size_t)e * HH * II;

    const int lane = tid & 63;
    const int w    = tid >> 6;
    const int wy   = w & 1;
    const int wx   = w >> 1;
    const int quad = lane >> 4;
    const int mcol = lane & 15;

    // per-lane B row pointers
    const float* pb0 = wb + (size_t)(n_base + wx * 32 + mcol) * II + quad * 8;
    const float* pb1 = pb0 + (size_t)16 * II;

    for (int m_base = 0; m_base < cnt; m_base += GM) {
        if (tid < GM) {
            int m = m_base + tid;
            sm->sl[tid] = (m < cnt) ? slots[e * CAP + m] : -1;
        }
        __syncthreads();

        const short* pa[4];
        #pragma unroll
        for (int i = 0; i < 4; ++i) {
            int s = sm->sl[wy * 64 + i * 16 + mcol];
            pa[i] = hmid + (size_t)(s >= 0 ? s : 0) * II + quad * 8;
        }

        floatx4 acc[4][2] = {};

        #pragma unroll 2
        for (int k0 = 0; k0 < II; k0 += GK) {
            short8v a[4];
            #pragma unroll
            for (int i = 0; i < 4; ++i) a[i] = *(const short8v*)(pa[i] + k0);
            float4 b00 = *(const float4*)(pb0 + k0);
            float4 b01 = *(const float4*)(pb0 + k0 + 4);
            float4 b10 = *(const float4*)(pb1 + k0);
            float4 b11 = *(const float4*)(pb1 + k0 + 4);
            short8v b0 = pack8(b00, b01);
            short8v b1 = pack8(b10, b11);
            #pragma unroll
            for (int i = 0; i < 4; ++i) {
                acc[i][0] = __builtin_amdgcn_mfma_f32_16x16x32_bf16(a[i], b0, acc[i][0], 0, 0, 0);
                acc[i][1] = __builtin_amdgcn_mfma_f32_16x16x32_bf16(a[i], b1, acc[i][1], 0, 0, 0);
            }
        }

        #pragma unroll
        for (int i = 0; i < 4; ++i) {
            #pragma unroll
            for (int r = 0; r < 4; ++r) {
                int m = wy * 64 + i * 16 + quad * 4 + r;
                int s = sm->sl[m];
                if (s < 0) continue;
                short* yrow = ydown + (size_t)s * HH + n_base + wx * 32;
                #pragma unroll
                for (int j = 0; j < 2; ++j)
                    yrow[j * 16 + mcol] = f2bf(acc[i][j][r]);
            }
        }
        __syncthreads();
    }
}

// ================= Phase D: combine ===========================================
static __device__ __forceinline__ void phaseD(
    const int bx, const int tid,
    const float* __restrict__ x, const short* __restrict__ ydown,
    const int* __restrict__ kexp, const float* __restrict__ zero_w,
    float* __restrict__ out)
{
    #pragma unroll
    for (int j = 0; j < 2; ++j) {
        const int t = bx * 2 + j;
        const float4 xvv = ((const float4*)(x + (size_t)t * HH))[tid];
        const float zw = zero_w[t];
        float4 o;
        o.x = zw * xvv.x; o.y = zw * xvv.y; o.z = zw * xvv.z; o.w = zw * xvv.w;
        #pragma unroll
        for (int k = 0; k < TOPK; ++k) {
            int slot = t * TOPK + k;
            if (kexp[slot] < EE) {
                short4v y = *(const short4v*)&ydown[(size_t)slot * HH + tid * 4];
                o.x += bf2f(y[0]); o.y += bf2f(y[1]);
                o.z += bf2f(y[2]); o.w += bf2f(y[3]);
            }
        }
        ((float4*)(out + (size_t)t * HH))[tid] = o;
    }
}

// ================= fused cooperative kernel ===================================
__global__ __launch_bounds__(256, 2) void fused_moe(
    const float* __restrict__ x, const float* __restrict__ rw,
    const float* __restrict__ bias, const float* __restrict__ wgu,
    const float* __restrict__ wd, float* __restrict__ out,
    int* __restrict__ counts, float* __restrict__ topk_w,
    float* __restrict__ zero_w, int* __restrict__ kexp,
    int* __restrict__ slots, short* __restrict__ xb,
    short* __restrict__ hmid, short* __restrict__ ydown)
{
    cg::grid_group grid = cg::this_grid();
    __shared__ SMem sm;
    const int bx = blockIdx.x, tid = threadIdx.x;

    phaseA(bx, tid, x, rw, bias, topk_w, zero_w, kexp, counts, slots, xb);
    __threadfence(); grid.sync();
    phaseB(bx, tid, &sm, xb, wgu, counts, slots, topk_w, hmid);
    __threadfence(); grid.sync();
    phaseC(bx, tid, &sm, hmid, wd, counts, slots, ydown);
    __threadfence(); grid.sync();
    phaseD(bx, tid, x, ydown, kexp, zero_w, out);
}

// ================= fallback: phases as separate kernels =======================
__global__ __launch_bounds__(256, 2) void kA(
    const float* __restrict__ x, const float* __restrict__ rw,
    const float* __restrict__ bias, float* __restrict__ topk_w,
    float* __restrict__ zero_w, int* __restrict__ kexp,
    int* __restrict__ counts, int* __restrict__ slots, short* __restrict__ xb)
{
    phaseA(blockIdx.x, threadIdx.x, x, rw, bias, topk_w, zero_w, kexp, counts, slots, xb);
}
__global__ __launch_bounds__(256, 2) void kB(
    const short* __restrict__ xb, const float* __restrict__ wgu,
    const int* __restrict__ counts, const int* __restrict__ slots,
    const float* __restrict__ topk_w, short* __restrict__ hmid)
{
    __shared__ SMem sm;
    phaseB(blockIdx.x, threadIdx.x, &sm, xb, wgu, counts, slots, topk_w, hmid);
}
__global__ __launch_bounds__(256, 2) void kC(
    const short* __restrict__ hmid, const float* __restrict__ wd,
    const int* __restrict__ counts, const int* __restrict__ slots,
    short* __restrict__ ydown)
{
    __shared__ SMem sm;
    phaseC(blockIdx.x, threadIdx.x, &sm, hmid, wd, counts, slots, ydown);
}
__global__ __launch_bounds__(256, 2) void kD(
    const float* __restrict__ x, const short* __restrict__ ydown,
    const int* __restrict__ kexp, const float* __restrict__ zero_w,
    float* __restrict__ out)
{
    phaseD(blockIdx.x, threadIdx.x, x, ydown, kexp, zero_w, out);
}

extern "C" void kernel_launch(void* const* d_in, const int* in_sizes, int n_in,
                              void* d_out, int out_size, void* d_ws, size_t ws_size,
                              hipStream_t stream) {
    const float* x    = (const float*)d_in[0];
    const float* rw   = (const float*)d_in[1];
    const float* bias = (const float*)d_in[2];
    const float* wgu  = (const float*)d_in[3];
    const float* wd   = (const float*)d_in[4];
    float* out = (float*)d_out;

    char* ws = (char*)d_ws;
    int*   counts = (int*)ws;
    float* topk_w = (float*)(ws + 1024);
    float* zero_w = (float*)(ws + 17408);
    int*   kexp   = (int*)(ws + 21504);
    int*   slots  = (int*)(ws + 40960);
    short* xb     = (short*)(ws + 262144);
    short* hmid   = (short*)(ws + 2359296);
    short* ydown  = (short*)(ws + 6553600);

    hipMemsetAsync(counts, 0, EE * sizeof(int), stream);

    int nb = 0;
    hipError_t qerr = hipOccupancyMaxActiveBlocksPerMultiprocessor(&nb, fused_moe, 256, 0);
    bool launched = false;
    if (qerr == hipSuccess && nb >= 2) {
        void* args[] = {
            (void*)&x, (void*)&rw, (void*)&bias, (void*)&wgu, (void*)&wd,
            (void*)&out, (void*)&counts, (void*)&topk_w, (void*)&zero_w,
            (void*)&kexp, (void*)&slots, (void*)&xb, (void*)&hmid, (void*)&ydown
        };
        hipError_t lerr = hipLaunchCooperativeKernel((const void*)fused_moe,
                                                     dim3(512), dim3(256),
                                                     args, 0, stream);
        launched = (lerr == hipSuccess);
    }
    if (!launched) {
        kA<<<dim3(512), dim3(256), 0, stream>>>(x, rw, bias, topk_w, zero_w, kexp, counts, slots, xb);
        kB<<<dim3(512), dim3(256), 0, stream>>>(xb, wgu, counts, slots, topk_w, hmid);
        kC<<<dim3(512), dim3(256), 0, stream>>>(hmid, wd, counts, slots, ydown);
        kD<<<dim3(512), dim3(256), 0, stream>>>(x, ydown, kexp, zero_w, out);
    }
}